// Round 1
// baseline (24115.715 us; speedup 1.0000x reference)
//
#include <hip/hip_runtime.h>
#include <hip/hip_bf16.h>

// SimpleLSTM on MI355X — persistent-kernel design, round 1.
//   B=64, S=512, I=512, H=1024, gates = 4H = 4096
// Strategy:
//   * 4 independent batch-groups (16 batches each) x 64 CUs = 256 blocks, 1/CU.
//   * Each CU owns 16 h-columns (=> 64 gate columns). Weights (Wx, Wh slices)
//     preloaded into VGPRs as bf16 MFMA B-fragments. Zero steady-state weight traffic.
//   * Per step: acc = x_t@Wx (barrier-independent, hides wait) ; group barrier ;
//     acc += h_{t-1}@Wh ; gates -> LDS ; elementwise (c,h) ; write h (fp32 out,
//     bf16 exchange) ; device-scope release ; next step.
//   * h exchange double-buffered in d_ws; one cumulative counter barrier per
//     group per step (monotone, reset by hipMemsetAsync each launch).

#define BATCH 64
#define SEQ   512
#define ISZ   512
#define HSZ   1024
#define G4    4096

typedef short bf16x8 __attribute__((ext_vector_type(8)));
typedef float f32x4  __attribute__((ext_vector_type(4)));

#define HEX_BYTES (2 * BATCH * HSZ * 2)   // 2 buffers x [64][1024] bf16 = 256 KB
#define CNT_STRIDE 64                     // uints between group counters (256 B)

static __device__ __forceinline__ short f2bf(float f) {
    __hip_bfloat16 h = __float2bfloat16(f);
    return *reinterpret_cast<short*>(&h);
}
static __device__ __forceinline__ float sigm(float x) {
    return 1.f / (1.f + __expf(-x));
}
static __device__ __forceinline__ float tanh_fast(float x) {
    x = fminf(15.f, fmaxf(-15.f, x));
    float e = __expf(2.f * x);
    return (e - 1.f) / (e + 1.f);
}

__global__ __launch_bounds__(512) void lstm_persistent(
    const float* __restrict__ x,     // [B][S][I] fp32
    const float* __restrict__ W,     // [I+H][4H] fp32
    const float* __restrict__ bias,  // [4H] fp32
    float* __restrict__ out,         // [B][S][H] outputs, then [B][H] h, [B][H] c
    unsigned short* __restrict__ hex,// [2][B][H] bf16 exchange
    unsigned int* __restrict__ cnt)  // group counters, stride CNT_STRIDE
{
    const int tid  = threadIdx.x;
    const int bid  = blockIdx.x;
    const int q    = bid & 63;          // CU index within group (owns h cols q*16..+16)
    const int g    = bid >> 6;          // batch group 0..3
    const int w    = tid >> 6;          // wave 0..7
    const int lane = tid & 63;
    const int gb   = w & 3;             // gate block: 0=f 1=i 2=c~ 3=o
    const int kh   = w >> 2;            // K-half split across wave pairs
    const int m16  = lane & 15;
    const int quad = lane >> 4;
    const int batch0 = g * 16;
    const int colbase = gb * 1024 + q * 16;   // gate column base for this wave

    // ---- preload weights into registers as MFMA B-fragments ----
    // B-frag layout (16x16x32 bf16): lane holds B[k = quad*8 + j][n = lane&15]
    bf16x8 wh[16];   // Wh[kh*512 .. +512][colbase..+16], 16 K-chunks of 32
    bf16x8 wx[8];    // Wx[kh*256 .. +256][colbase..+16],  8 K-chunks of 32
    {
        const int n = m16;
        #pragma unroll
        for (int kk = 0; kk < 16; ++kk) {
            #pragma unroll
            for (int j = 0; j < 8; ++j) {
                int k = kh * 512 + kk * 32 + quad * 8 + j;
                wh[kk][j] = f2bf(W[(size_t)(ISZ + k) * G4 + colbase + n]);
            }
        }
        #pragma unroll
        for (int kk = 0; kk < 8; ++kk) {
            #pragma unroll
            for (int j = 0; j < 8; ++j) {
                int k = kh * 256 + kk * 32 + quad * 8 + j;
                wx[kk][j] = f2bf(W[(size_t)k * G4 + colbase + n]);
            }
        }
    }

    // elementwise mapping (tid < 256): m = tid>>4 (batch-in-group), n = tid&15 (col)
    const int em = tid >> 4;   // only meaningful when tid < 256
    const int en = tid & 15;
    float bia[4];
    #pragma unroll
    for (int gg = 0; gg < 4; ++gg) bia[gg] = bias[gg * 1024 + q * 16 + en];

    float c_state = 0.f;

    __shared__ float gtile[8][16][17];   // 8 wave D-tiles, 16x16 fp32, +1 pad

    unsigned int* mycnt = cnt + (size_t)g * CNT_STRIDE;

    for (int t = 0; t < SEQ; ++t) {
        // ---- x part (no dependence on h_{t-1}) ----
        f32x4 acc = {0.f, 0.f, 0.f, 0.f};
        {
            const float* xrow = x + ((size_t)(batch0 + m16) * SEQ + t) * ISZ
                                  + kh * 256 + quad * 8;
            #pragma unroll
            for (int kk = 0; kk < 8; ++kk) {
                f32x4 x0 = *(const f32x4*)(xrow + kk * 32);
                f32x4 x1 = *(const f32x4*)(xrow + kk * 32 + 4);
                bf16x8 a;
                a[0] = f2bf(x0[0]); a[1] = f2bf(x0[1]);
                a[2] = f2bf(x0[2]); a[3] = f2bf(x0[3]);
                a[4] = f2bf(x1[0]); a[5] = f2bf(x1[1]);
                a[6] = f2bf(x1[2]); a[7] = f2bf(x1[3]);
                acc = __builtin_amdgcn_mfma_f32_16x16x32_bf16(a, wx[kk], acc, 0, 0, 0);
            }
        }

        // ---- wait: all 64 CUs of this group finished step t-1 ----
        if (tid == 0) {
            const unsigned int target = 64u * (unsigned int)t;
            long long guard = 0;
            while (__hip_atomic_load(mycnt, __ATOMIC_ACQUIRE,
                                     __HIP_MEMORY_SCOPE_AGENT) < target) {
                __builtin_amdgcn_s_sleep(2);
                if (++guard > (1LL << 27)) break;   // anti-hang safety valve
            }
        }
        __syncthreads();

        // ---- h part: acc += h_{t-1} @ Wh ----
        {
            const int rb = (t + 1) & 1;   // buffer holding h_{t-1}
            const unsigned short* hrow = hex + ((size_t)rb * BATCH + batch0 + m16) * HSZ
                                             + kh * 512 + quad * 8;
            #pragma unroll
            for (int kk = 0; kk < 16; ++kk) {
                bf16x8 a = *(const bf16x8*)(hrow + kk * 32);
                acc = __builtin_amdgcn_mfma_f32_16x16x32_bf16(a, wh[kk], acc, 0, 0, 0);
            }
        }

        // ---- D tile -> LDS (C/D layout: col = lane&15, row = quad*4 + reg) ----
        #pragma unroll
        for (int r = 0; r < 4; ++r)
            gtile[w][quad * 4 + r][m16] = acc[r];
        __syncthreads();

        // ---- elementwise gate math (256 threads = 16 batches x 16 cols) ----
        if (tid < 256) {
            float gf = gtile[0][em][en] + gtile[4][em][en] + bia[0];
            float gi = gtile[1][em][en] + gtile[5][em][en] + bia[1];
            float gc = gtile[2][em][en] + gtile[6][em][en] + bia[2];
            float go = gtile[3][em][en] + gtile[7][em][en] + bia[3];
            float f  = sigm(gf);
            float i  = sigm(gi);
            float ct = tanh_fast(gc);
            float o  = sigm(go);
            c_state  = f * c_state + i * ct;
            float h  = o * tanh_fast(c_state);

            out[((size_t)(batch0 + em) * SEQ + t) * HSZ + q * 16 + en] = h;

            const int wb = t & 1;
            hex[((size_t)wb * BATCH + batch0 + em) * HSZ + q * 16 + en] =
                (unsigned short)f2bf(h);

            if (t == SEQ - 1) {
                size_t fin = (size_t)BATCH * SEQ * HSZ;
                out[fin + (size_t)(batch0 + em) * HSZ + q * 16 + en] = h;
                out[fin + (size_t)BATCH * HSZ + (size_t)(batch0 + em) * HSZ
                        + q * 16 + en] = c_state;
            }
        }

        // ---- publish h_t ----
        __threadfence();
        __syncthreads();
        if (tid == 0) {
            __hip_atomic_fetch_add(mycnt, 1u, __ATOMIC_RELEASE,
                                   __HIP_MEMORY_SCOPE_AGENT);
        }
    }
}

extern "C" void kernel_launch(void* const* d_in, const int* in_sizes, int n_in,
                              void* d_out, int out_size, void* d_ws, size_t ws_size,
                              hipStream_t stream) {
    const float* x    = (const float*)d_in[0];
    const float* W    = (const float*)d_in[1];
    const float* bias = (const float*)d_in[2];
    float* out        = (float*)d_out;

    unsigned short* hex = (unsigned short*)d_ws;
    unsigned int*   cnt = (unsigned int*)((char*)d_ws + HEX_BYTES);

    // zero h0 exchange buffers + group barrier counters (ws is re-poisoned 0xAA
    // before every timed launch, so this must run every call; it is graph-legal)
    hipMemsetAsync(d_ws, 0, HEX_BYTES + 4 * CNT_STRIDE * sizeof(unsigned int), stream);

    lstm_persistent<<<256, 512, 0, stream>>>(x, W, bias, out, hex, cnt);
}